// Round 1
// baseline (312.007 us; speedup 1.0000x reference)
//
#include <hip/hip_runtime.h>

#define Bb 8
#define Nn 64
#define Hh 152
#define Ww 272
#define HW (Hh * Ww)
#define EMB 128
#define NC 500
#define EPSV 1e-4f

// ---------------------------------------------------------------------------
// Kernel 1: heatmap focal loss over B*H*W pixels.
// gt_hm reconstructed per-pixel from the 64 centers (LDS) with the 5-tap
// gaussian table. pos test (gt_hm==1.0f) is robust: center tap is exactly 1.0,
// min product of two taps is 0.641 so multi-touch pixels are >= 1.28.
// ---------------------------------------------------------------------------
__global__ void hm_loss_kernel(const float* __restrict__ hm,
                               const float* __restrict__ gt,
                               float* __restrict__ acc) {
    __shared__ int s_r[Nn];
    __shared__ int s_c[Nn];
    const int b = blockIdx.x;
    const int t = threadIdx.x;

    if (t < Nn) {
        const float* g5 = gt + ((size_t)b * Nn + t) * 5;
        float xc = g5[1], yc = g5[2];
        float rf = yc * (float)Hh;
        float cf = xc * (float)Ww;
        int rr = (int)floorf(rf); rr = min(max(rr, 0), Hh - 1);
        int cc = (int)floorf(cf); cc = min(max(cc, 0), Ww - 1);
        s_r[t] = rr;
        s_c[t] = cc;
    }
    __syncthreads();

    // gaussian taps: exp(-((i-2)/3)^2 / 2); tap[2] == 1.0f exactly
    float g[5];
#pragma unroll
    for (int i = 0; i < 5; ++i) {
        float tv = (float)(i - 2) / 3.0f;
        g[i] = expf(-0.5f * tv * tv);
    }

    float pos_l = 0.0f, neg_l = 0.0f, np = 0.0f;
    const float* hmb = hm + (size_t)b * HW;

    for (int p = blockIdx.y * blockDim.x + t; p < HW; p += gridDim.y * blockDim.x) {
        int y = p / Ww;
        int x = p - y * Ww;
        float h = hmb[p];
        float pred = 1.0f / (1.0f + expf(-h));
        pred = fminf(fmaxf(pred, EPSV), 1.0f - EPSV);

        float gh = 0.0f;
#pragma unroll 8
        for (int n = 0; n < Nn; ++n) {
            int dy = y - s_r[n];
            int dx = x - s_c[n];
            if (dy >= -2 && dy <= 2 && dx >= -2 && dx <= 2)
                gh += g[dy + 2] * g[dx + 2];
        }

        if (gh == 1.0f) {
            float om = 1.0f - pred;
            pos_l += om * om * logf(pred);
            np += 1.0f;
        } else if (gh < 1.0f) {
            float om = 1.0f - gh;
            float w = om * om;
            w = w * w;
            neg_l += w * pred * pred * logf(1.0f - pred);
        }
    }

    // wave(64) reduce, then one atomic per wave
#pragma unroll
    for (int off = 32; off > 0; off >>= 1) {
        pos_l += __shfl_down(pos_l, off);
        neg_l += __shfl_down(neg_l, off);
        np    += __shfl_down(np, off);
    }
    if ((t & 63) == 0) {
        atomicAdd(&acc[2], pos_l);
        atomicAdd(&acc[3], neg_l);
        atomicAdd(&acc[4], np);
    }
}

// ---------------------------------------------------------------------------
// Kernel 2: per-sample (B*N=512 blocks): ReID CE + box/offset L1 terms.
// ---------------------------------------------------------------------------
__global__ void sample_kernel(const float* __restrict__ bs,
                              const float* __restrict__ off,
                              const float* __restrict__ reid,
                              const float* __restrict__ gt,
                              const float* __restrict__ Wc,
                              const float* __restrict__ bc,
                              float* __restrict__ acc) {
    const int s = blockIdx.x;          // 0..B*N-1
    const int b = s / Nn;
    const int t = threadIdx.x;

    __shared__ float s_feat[EMB];
    __shared__ float s_log[NC];
    __shared__ float s_red[256];

    const float* g5 = gt + (size_t)s * 5;
    const float tf = g5[0];
    const float xc = g5[1], yc = g5[2];
    const float bw = g5[3], bh = g5[4];

    const float rf = yc * (float)Hh;
    const float cf = xc * (float)Ww;
    const float fr = floorf(rf);
    const float fc = floorf(cf);
    const int rr = min(max((int)fr, 0), Hh - 1);
    const int cc = min(max((int)fc, 0), Ww - 1);
    const size_t pix = (size_t)rr * Ww + cc;

    if (t < EMB)
        s_feat[t] = reid[(size_t)b * EMB * HW + (size_t)t * HW + pix];
    __syncthreads();

    // logits for classes t, t+256 (all threads own >= 1 class since NC=500)
    float lmax = -INFINITY;
    for (int c = t; c < NC; c += 256) {
        float d = bc[c];
        const float* wr = Wc + (size_t)c * EMB;
#pragma unroll 8
        for (int k = 0; k < EMB; ++k)
            d += s_feat[k] * wr[k];
        s_log[c] = d;
        lmax = fmaxf(lmax, d);
    }

    s_red[t] = lmax;
    __syncthreads();
#pragma unroll
    for (int w = 128; w > 0; w >>= 1) {
        if (t < w) s_red[t] = fmaxf(s_red[t], s_red[t + w]);
        __syncthreads();
    }
    const float mv = s_red[0];
    __syncthreads();

    float lsum = 0.0f;
    for (int c = t; c < NC; c += 256)
        lsum += expf(s_log[c] - mv);
    s_red[t] = lsum;
    __syncthreads();
#pragma unroll
    for (int w = 128; w > 0; w >>= 1) {
        if (t < w) s_red[t] += s_red[t + w];
        __syncthreads();
    }

    if (t == 0) {
        int lab = (tf > (float)NC) ? (NC - 1) : ((int)tf - 1);
        lab = min(max(lab, 0), NC - 1);
        float ce = logf(s_red[0]) + mv - s_log[lab];
        atomicAdd(&acc[5], ce);

        // box-size + offset L1 at this center
        const float* bsb = bs  + (size_t)b * 2 * HW;
        const float* ofb = off + (size_t)b * 2 * HW;
        float bl = fabsf(bsb[pix]      - bh * 608.0f)
                 + fabsf(bsb[HW + pix] - bw * 1088.0f);
        float ol = fabsf(ofb[pix]      - (rf - fr))
                 + fabsf(ofb[HW + pix] - (cf - fc));
        atomicAdd(&acc[0], bl);
        atomicAdd(&acc[1], ol);
    }
}

// ---------------------------------------------------------------------------
// Kernel 3: finalize the 6 scalars.
// out = (bs_loss, off_loss, det_loss, hm_loss, reid_loss, total)
// ---------------------------------------------------------------------------
__global__ void finalize_kernel(const float* __restrict__ acc,
                                float* __restrict__ out) {
    const float bsl = acc[0];
    const float ofl = acc[1];
    const float pl  = acc[2];
    const float nl  = acc[3];
    const float np  = acc[4];
    const float re  = acc[5];
    const float hm  = (np >= 1.0f) ? (-(pl + nl) / np) : (-nl);
    const float reid = re / (float)Nn;
    const float det  = hm + 0.1f * bsl + ofl;
    out[0] = bsl;
    out[1] = ofl;
    out[2] = det;
    out[3] = hm;
    out[4] = reid;
    out[5] = det + reid;
}

extern "C" void kernel_launch(void* const* d_in, const int* in_sizes, int n_in,
                              void* d_out, int out_size, void* d_ws, size_t ws_size,
                              hipStream_t stream) {
    const float* hm   = (const float*)d_in[0];  // (B,1,H,W)
    const float* bs   = (const float*)d_in[1];  // (B,2,H,W)
    const float* off  = (const float*)d_in[2];  // (B,2,H,W)
    const float* reid = (const float*)d_in[3];  // (B,128,H,W)
    const float* gt   = (const float*)d_in[4];  // (B,N,5)
    const float* Wc   = (const float*)d_in[5];  // (500,128)
    const float* bc   = (const float*)d_in[6];  // (500,)
    float* out = (float*)d_out;
    float* acc = (float*)d_ws;                  // 6 accumulators

    hipMemsetAsync(acc, 0, 8 * sizeof(float), stream);

    hipLaunchKernelGGL(hm_loss_kernel, dim3(Bb, 32), dim3(256), 0, stream,
                       hm, gt, acc);
    hipLaunchKernelGGL(sample_kernel, dim3(Bb * Nn), dim3(256), 0, stream,
                       bs, off, reid, gt, Wc, bc, acc);
    hipLaunchKernelGGL(finalize_kernel, dim3(1), dim3(1), 0, stream,
                       acc, out);
}